// Round 1
// baseline (582.503 us; speedup 1.0000x reference)
//
#include <hip/hip_runtime.h>

#define BB 2
#define CIN 32
#define COUT 32
#define KK 9
#define IH 256
#define IW 256
#define PIX (IH*IW)        // 65536 input pixels
#define OH 512
#define OW 512
#define OHOW (OH*OW)       // 262144 output pixels
#define NCH 64             // B*COUT channel combos
#define TP 64              // input pixels per block
#define XPAD 68            // 68*4=272B row stride: 16B-aligned, 8-way write conflict only

// One block: TP input pixels, 9 waves (wave w handles tap k=w), lane = channel c=b*32+o.
__global__ __launch_bounds__(576) void mtc_scatter(
    const float* __restrict__ x, const float* __restrict__ weight,
    const float* __restrict__ smap, float* __restrict__ acc, int chlast)
{
    __shared__ float xs[TP][XPAD];      // xs[pp][b*32+i] = x[b][i][p0+pp]
    __shared__ float sm[TP * KK * 2];   // sample_map tile, contiguous [pp][k][2]

    const int t  = threadIdx.x;
    const int p0 = blockIdx.x * TP;

    // ---- stage x tile: coalesced global reads (lane-contiguous pp) ----
    if (t < 512) {
        const int pp = t & 63;
        const int c0 = t >> 6;          // 0..7
        #pragma unroll
        for (int ch = 0; ch < 8; ++ch) {
            const int c = c0 + ch * 8;  // covers 0..63
            xs[pp][c] = x[(size_t)c * PIX + p0 + pp];
        }
    }
    // ---- stage sample_map tile: fully contiguous 1152 floats ----
    for (int i = t; i < TP * KK * 2; i += 576)
        sm[i] = smap[(size_t)p0 * (KK * 2) + i];

    // ---- per-lane W fragment in registers (fixed o,k for this lane/wave) ----
    const int k    = t >> 6;            // wave id = tap index, 0..8
    const int lane = t & 63;            // channel c = b*32 + o
    const int b    = lane >> 5;
    const int o    = lane & 31;
    float wreg[CIN];
    #pragma unroll
    for (int i = 0; i < CIN; ++i)
        wreg[i] = weight[(i * COUT + o) * KK + k];

    __syncthreads();

    const float* xrow_base = &xs[0][b * 32];

    #pragma unroll 4
    for (int pp = 0; pp < TP; ++pp) {
        // wave-uniform bilinear setup (broadcast LDS reads)
        const float sx = sm[(pp * KK + k) * 2 + 0];
        const float sy = sm[(pp * KK + k) * 2 + 1];
        const float x0f = floorf(sx), y0f = floorf(sy);
        const float dx = sx - x0f, dy = sy - y0f;
        int x0 = (int)x0f, y0 = (int)y0f;
        x0 = min(max(x0, 0), OW - 1);
        y0 = min(max(y0, 0), OH - 1);
        const int x1 = min(x0 + 1, OW - 1);
        const int y1 = min(y0 + 1, OH - 1);

        // contrib[b,o,k,p] = sum_i x[b,i,p] * W[i,o,k] : 8x ds_read_b128 broadcast + 32 FMA
        const float* xrow = xrow_base + (size_t)pp * XPAD;
        float cv = 0.f;
        #pragma unroll
        for (int j = 0; j < 8; ++j) {
            const float4 xv = *(const float4*)(xrow + 4 * j);
            cv += xv.x * wreg[4*j] + xv.y * wreg[4*j+1]
                + xv.z * wreg[4*j+2] + xv.w * wreg[4*j+3];
        }

        const float w00 = (1.f - dx) * (1.f - dy);
        const float w10 = dx * (1.f - dy);
        const float w01 = (1.f - dx) * dy;
        const float w11 = dx * dy;
        const int q00 = y0 * OW + x0, q10 = y0 * OW + x1;
        const int q01 = y1 * OW + x0, q11 = y1 * OW + x1;

        if (chlast) {
            // channels-last: 64 lanes hit 256B contiguous -> coalesced wave-atomic
            atomicAdd(&acc[(size_t)q00 * NCH + lane], cv * w00);
            atomicAdd(&acc[(size_t)q10 * NCH + lane], cv * w10);
            atomicAdd(&acc[(size_t)q01 * NCH + lane], cv * w01);
            atomicAdd(&acc[(size_t)q11 * NCH + lane], cv * w11);
        } else {
            const size_t base = (size_t)lane * OHOW;
            atomicAdd(&acc[base + q00], cv * w00);
            atomicAdd(&acc[base + q10], cv * w10);
            atomicAdd(&acc[base + q01], cv * w01);
            atomicAdd(&acc[base + q11], cv * w11);
        }
    }
}

// acc[q][c] -> out[c][q] (+bias), 64x64 LDS tile transpose, conflict-free (+1 pad)
__global__ __launch_bounds__(256) void mtc_untranspose_bias(
    const float* __restrict__ acc, const float* __restrict__ bias,
    float* __restrict__ out)
{
    __shared__ float tile[64][65];
    const int t  = threadIdx.x;
    const int q0 = blockIdx.x * 64;
    const int tx = t & 63;      // lane
    const int ty = t >> 6;      // wave 0..3

    #pragma unroll
    for (int r = 0; r < 16; ++r) {
        const int qq = ty + 4 * r;
        tile[qq][tx] = acc[(size_t)(q0 + qq) * NCH + tx];   // coalesced
    }
    __syncthreads();
    #pragma unroll
    for (int r = 0; r < 16; ++r) {
        const int c = ty + 4 * r;                            // out channel index b*32+o
        out[(size_t)c * OHOW + q0 + tx] = tile[tx][c] + bias[c & 31];  // coalesced
    }
}

__global__ __launch_bounds__(256) void mtc_bias_add(
    float* __restrict__ out, const float* __restrict__ bias)
{
    const size_t i = (size_t)blockIdx.x * 256 + threadIdx.x;
    out[i] += bias[(i >> 18) & 31];   // layout [b][o][q], q-span 2^18
}

extern "C" void kernel_launch(void* const* d_in, const int* in_sizes, int n_in,
                              void* d_out, int out_size, void* d_ws, size_t ws_size,
                              hipStream_t stream) {
    const float* x      = (const float*)d_in[0];
    const float* weight = (const float*)d_in[1];
    const float* bias   = (const float*)d_in[2];
    const float* smap   = (const float*)d_in[3];
    float* out = (float*)d_out;

    const size_t accBytes = (size_t)OHOW * NCH * sizeof(float);  // 64 MiB

    if (ws_size >= accBytes) {
        float* acc = (float*)d_ws;
        hipMemsetAsync(acc, 0, accBytes, stream);
        mtc_scatter<<<PIX / TP, 576, 0, stream>>>(x, weight, smap, acc, 1);
        mtc_untranspose_bias<<<OHOW / 64, 256, 0, stream>>>(acc, bias, out);
    } else {
        // fallback: accumulate directly in d_out's native layout
        hipMemsetAsync(out, 0, accBytes, stream);
        mtc_scatter<<<PIX / TP, 576, 0, stream>>>(x, weight, smap, out, 0);
        mtc_bias_add<<<(OHOW * NCH) / 256, 256, 0, stream>>>(out, bias);
    }
}